// Round 1
// baseline (13607.417 us; speedup 1.0000x reference)
//
#include <hip/hip_runtime.h>

#define HID 128
#define NLAYER 4

// ---------------------------------------------------------------------------
// lower_bound on sorted int array
// ---------------------------------------------------------------------------
__device__ __forceinline__ int lowbound(const int* __restrict__ a, int n, int v) {
    int lo = 0, hi = n;
    while (lo < hi) {
        int mid = (lo + hi) >> 1;
        if (a[mid] < v) lo = mid + 1; else hi = mid;
    }
    return lo;
}

// ---------------------------------------------------------------------------
// Atom encoder: h = x @ aW + ab ; also z = (1+eps[l=0]) * h   (layer-0 init)
// grid.z = slot (encoder within this launch), enc = enc0 + slot
// ---------------------------------------------------------------------------
__global__ void atom_kernel(const float* __restrict__ dx, const float* __restrict__ sx,
                            const float* __restrict__ aW, const float* __restrict__ ab,
                            const float* __restrict__ eps,
                            float* __restrict__ h, float* __restrict__ z,
                            int N, int enc0) {
    const int slot = blockIdx.z;
    const int enc  = enc0 + slot;
    long idx = (long)blockIdx.x * blockDim.x + threadIdx.x;
    if (idx >= (long)N * HID) return;
    const int n = (int)(idx / HID), c = (int)(idx % HID);
    const float* x = (enc < 2) ? dx : sx;
    const float* W = aW + (size_t)enc * 9 * HID;
    float acc = ab[enc * HID + c];
#pragma unroll
    for (int k = 0; k < 9; k++) acc = fmaf(x[n * 9 + k], W[k * HID + c], acc);
    size_t off = (size_t)slot * N * HID + idx;
    h[off] = acc;
    z[off] = acc * (1.f + eps[enc * NLAYER + 0]);
}

// ---------------------------------------------------------------------------
// Scatter-add: z[dst] += h[src]  (z pre-initialized to (1+eps)*h)
// 32 threads per edge, 4 channels each (float4 gather, 4 atomics)
// ---------------------------------------------------------------------------
__global__ void scatter_kernel(const int* __restrict__ de, const int* __restrict__ se,
                               const float* __restrict__ h, float* __restrict__ z,
                               int N, int E, int enc0) {
    const int slot = blockIdx.z;
    const int enc  = enc0 + slot;
    long g = (long)blockIdx.x * blockDim.x + threadIdx.x;
    if (g >= (long)E * 32) return;
    const int e = (int)(g >> 5);
    const int c = (int)(g & 31) * 4;
    const int* ei = (enc < 2) ? de : se;
    const int src = ei[e];
    const int dst = ei[E + e];
    const float4 hv = *(const float4*)&h[(size_t)slot * N * HID + (size_t)src * HID + c];
    float* zp = &z[(size_t)slot * N * HID + (size_t)dst * HID + c];
    atomicAdd(zp + 0, hv.x);
    atomicAdd(zp + 1, hv.y);
    atomicAdd(zp + 2, hv.z);
    atomicAdd(zp + 3, hv.w);
}

// ---------------------------------------------------------------------------
// GEMM + bias + BN + ReLU epilogue.  out = relu((A@W + bias - m)*g/sqrt(v+1e-5) + b)
// Optionally also writes zout = out * (1 + eps[enc][l+1])  (next layer's z init).
// A: [M, KDIM] row-major (per-slot stride M*KDIM). W: [3][L][KDIM][Nout].
// Tile 64x64, K-chunk 16, 256 threads, 4x4 micro-tile.
// ---------------------------------------------------------------------------
template <int KDIM>
__global__ __launch_bounds__(256) void gemm_bn_relu(
    const float* __restrict__ A, const float* __restrict__ Wt,
    const float* __restrict__ bias,
    const float* __restrict__ bng, const float* __restrict__ bnb,
    const float* __restrict__ bnm, const float* __restrict__ bnv,
    float* __restrict__ out, float* __restrict__ zout,
    const float* __restrict__ eps,
    int M, int Nout, int l, int enc0, int wz) {
    const int slot = blockIdx.z;
    const int enc  = enc0 + slot;
    const float* Ap = A + (size_t)slot * M * KDIM;
    const float* Wp = Wt + ((size_t)enc * NLAYER + l) * (size_t)KDIM * Nout;
    const size_t poff = ((size_t)enc * NLAYER + l) * (size_t)Nout;

    __shared__ float As[16][68];  // [k][m], padded row for alignment
    __shared__ float Bs[16][64];  // [k][n]
    const int tid = threadIdx.x;
    const int tx = tid & 15, ty = tid >> 4;
    const int m0 = blockIdx.x * 64, n0 = blockIdx.y * 64;

    float acc[4][4] = {{0.f}};

    for (int k0 = 0; k0 < KDIM; k0 += 16) {
        __syncthreads();
        {   // A tile: 64 rows x 16 k, each thread one float4
            const int row = tid >> 2, c4 = (tid & 3) * 4;
            const int gr = m0 + row;
            float4 av = make_float4(0.f, 0.f, 0.f, 0.f);
            if (gr < M) av = *(const float4*)&Ap[(size_t)gr * KDIM + k0 + c4];
            As[c4 + 0][row] = av.x;
            As[c4 + 1][row] = av.y;
            As[c4 + 2][row] = av.z;
            As[c4 + 3][row] = av.w;
        }
        {   // B tile: 16 k x 64 n
            const int n = tid & 63;
#pragma unroll
            for (int i = 0; i < 4; i++) {
                const int kk = (tid >> 6) + i * 4;
                Bs[kk][n] = Wp[(size_t)(k0 + kk) * Nout + n0 + n];
            }
        }
        __syncthreads();
#pragma unroll
        for (int kk = 0; kk < 16; kk++) {
            float4 a4 = *(const float4*)&As[kk][ty * 4];
            float4 b4 = *(const float4*)&Bs[kk][tx * 4];
            float a[4] = {a4.x, a4.y, a4.z, a4.w};
            float b[4] = {b4.x, b4.y, b4.z, b4.w};
#pragma unroll
            for (int i = 0; i < 4; i++)
#pragma unroll
                for (int j = 0; j < 4; j++) acc[i][j] = fmaf(a[i], b[j], acc[i][j]);
        }
    }

    // epilogue: per-column fused bias+BN scale/shift
    const int c0 = n0 + tx * 4;
    float4 f_b  = *(const float4*)&bias[poff + c0];
    float4 f_g  = *(const float4*)&bng[poff + c0];
    float4 f_be = *(const float4*)&bnb[poff + c0];
    float4 f_m  = *(const float4*)&bnm[poff + c0];
    float4 f_v  = *(const float4*)&bnv[poff + c0];
    float sc[4], sh[4];
    {
        float bb[4] = {f_b.x, f_b.y, f_b.z, f_b.w};
        float gg[4] = {f_g.x, f_g.y, f_g.z, f_g.w};
        float be[4] = {f_be.x, f_be.y, f_be.z, f_be.w};
        float mm[4] = {f_m.x, f_m.y, f_m.z, f_m.w};
        float vv[4] = {f_v.x, f_v.y, f_v.z, f_v.w};
#pragma unroll
        for (int j = 0; j < 4; j++) {
            sc[j] = gg[j] * rsqrtf(vv[j] + 1e-5f);
            sh[j] = (bb[j] - mm[j]) * sc[j] + be[j];
        }
    }
    float zs = 0.f;
    if (wz) zs = 1.f + eps[enc * NLAYER + l + 1];
    float* outp = out + (size_t)slot * M * Nout;
    float* zp   = wz ? (zout + (size_t)slot * M * Nout) : nullptr;
#pragma unroll
    for (int i = 0; i < 4; i++) {
        const int gr = m0 + ty * 4 + i;
        if (gr >= M) continue;
        float o[4];
#pragma unroll
        for (int j = 0; j < 4; j++) o[j] = fmaxf(fmaf(acc[i][j], sc[j], sh[j]), 0.f);
        float4 ov = make_float4(o[0], o[1], o[2], o[3]);
        *(float4*)&outp[(size_t)gr * Nout + c0] = ov;
        if (wz) {
            float4 zv = make_float4(o[0] * zs, o[1] * zs, o[2] * zs, o[3] * zs);
            *(float4*)&zp[(size_t)gr * Nout + c0] = zv;
        }
    }
}

// ---------------------------------------------------------------------------
// Segment-mean pool. bat is SORTED -> per-graph contiguous range via binary search.
// One block (128 threads = 128 channels) per graph.
// ---------------------------------------------------------------------------
__global__ __launch_bounds__(128) void pool_kernel(const int* __restrict__ db,
                                                   const int* __restrict__ sb,
                                                   const float* __restrict__ h,
                                                   float* __restrict__ emb,
                                                   int N, int B, int enc0) {
    const int slot = blockIdx.z;
    const int enc  = enc0 + slot;
    const int* bat = (enc < 2) ? db : sb;
    const int g = blockIdx.x;
    const int lo = lowbound(bat, N, g);
    const int hi = lowbound(bat, N, g + 1);
    const int c = threadIdx.x;
    float s = 0.f;
    const float* hp = h + (size_t)slot * N * HID;
    for (int n = lo; n < hi; n++) s += hp[(size_t)n * HID + c];
    const float cnt = (float)(hi - lo);
    emb[((size_t)enc * B + g) * HID + c] = s / fmaxf(cnt, 1.f);
}

// ---------------------------------------------------------------------------
// block reduction over 128 threads
// ---------------------------------------------------------------------------
__device__ __forceinline__ float block_sum128(float x, float* red, int tid) {
    red[tid] = x;
    __syncthreads();
    if (tid < 64) {
        float v = red[tid] + red[tid + 64];
#pragma unroll
        for (int o = 32; o > 0; o >>= 1) v += __shfl_down(v, o);
        if (tid == 0) red[0] = v;
    }
    __syncthreads();
    float r = red[0];
    __syncthreads();
    return r;
}

// ---------------------------------------------------------------------------
// Fusion head: one block (128 threads) per graph row.
//   inter = relu(LN([bs,so] @ int_W + int_b))
//   temp  = relu(t*tW1+tb1) @ tW2 + tb2
//   f     = [aq, inter, temp]  (288)
//   h1 = relu(LN(f @ fW1 + fb1)); h2 = relu(LN(h1 @ fW2 + fb2)); out = h2 @ fW3 + fb3
// ---------------------------------------------------------------------------
__global__ __launch_bounds__(128) void fusion_kernel(
    const float* __restrict__ emb, const float* __restrict__ t,
    const float* __restrict__ tW1, const float* __restrict__ tb1,
    const float* __restrict__ tW2, const float* __restrict__ tb2,
    const float* __restrict__ iW, const float* __restrict__ ib,
    const float* __restrict__ ilg, const float* __restrict__ ilb,
    const float* __restrict__ fW1, const float* __restrict__ fb1,
    const float* __restrict__ l1g, const float* __restrict__ l1b,
    const float* __restrict__ fW2, const float* __restrict__ fb2,
    const float* __restrict__ l2g, const float* __restrict__ l2b,
    const float* __restrict__ fW3, const float* __restrict__ fb3,
    float* __restrict__ out, int B) {
    const int r = blockIdx.x;
    const int tid = threadIdx.x;
    __shared__ float cs[256];    // [bs, so] concat
    __shared__ float cat[288];   // fusion vector [aq, inter, temp]
    __shared__ float buf[128];   // h1
    __shared__ float red[128];
    __shared__ float tmp32[32];

    cs[tid]        = emb[((size_t)1 * B + r) * HID + tid];
    cs[128 + tid]  = emb[((size_t)2 * B + r) * HID + tid];
    cat[tid]       = emb[((size_t)0 * B + r) * HID + tid];
    __syncthreads();

    // inter = relu(LN(cs @ iW + ib))
    float acc = ib[tid];
    for (int k = 0; k < 256; k++) acc = fmaf(cs[k], iW[k * HID + tid], acc);
    float mu  = block_sum128(acc, red, tid) * (1.f / 128.f);
    float d   = acc - mu;
    float var = block_sum128(d * d, red, tid) * (1.f / 128.f);
    float inter = fmaxf(d * rsqrtf(var + 1e-5f) * ilg[tid] + ilb[tid], 0.f);
    cat[128 + tid] = inter;

    // temp MLP
    if (tid < 32) tmp32[tid] = fmaxf(fmaf(t[r], tW1[tid], tb1[tid]), 0.f);
    __syncthreads();
    if (tid < 32) {
        float a2 = tb2[tid];
        for (int j = 0; j < 32; j++) a2 = fmaf(tmp32[j], tW2[j * 32 + tid], a2);
        cat[256 + tid] = a2;
    }
    __syncthreads();

    // h1 = relu(LN(cat @ fW1 + fb1))
    float a1 = fb1[tid];
    for (int k = 0; k < 288; k++) a1 = fmaf(cat[k], fW1[k * HID + tid], a1);
    mu  = block_sum128(a1, red, tid) * (1.f / 128.f);
    d   = a1 - mu;
    var = block_sum128(d * d, red, tid) * (1.f / 128.f);
    buf[tid] = fmaxf(d * rsqrtf(var + 1e-5f) * l1g[tid] + l1b[tid], 0.f);
    __syncthreads();

    // h2 = relu(LN(buf @ fW2 + fb2)), width 64
    float a2v = 0.f;
    if (tid < 64) {
        a2v = fb2[tid];
        for (int k = 0; k < 128; k++) a2v = fmaf(buf[k], fW2[k * 64 + tid], a2v);
    }
    mu = block_sum128((tid < 64) ? a2v : 0.f, red, tid) * (1.f / 64.f);
    float d2 = (tid < 64) ? (a2v - mu) : 0.f;
    var = block_sum128(d2 * d2, red, tid) * (1.f / 64.f);
    float contrib = 0.f;
    if (tid < 64) {
        float h2 = fmaxf(d2 * rsqrtf(var + 1e-5f) * l2g[tid] + l2b[tid], 0.f);
        contrib = h2 * fW3[tid];
    }
    float s = block_sum128(contrib, red, tid);
    if (tid == 0) out[r] = s + fb3[0];
}

// ---------------------------------------------------------------------------
extern "C" void kernel_launch(void* const* d_in, const int* in_sizes, int n_in,
                              void* d_out, int out_size, void* d_ws, size_t ws_size,
                              hipStream_t stream) {
    const float* dx  = (const float*)d_in[0];
    const int*   de  = (const int*)d_in[1];
    const int*   db  = (const int*)d_in[2];
    const float* sx  = (const float*)d_in[3];
    const int*   se  = (const int*)d_in[4];
    const int*   sb  = (const int*)d_in[5];
    const float* t   = (const float*)d_in[6];
    const float* aW  = (const float*)d_in[7];
    const float* ab  = (const float*)d_in[8];
    const float* eps = (const float*)d_in[9];
    const float* W1  = (const float*)d_in[10];
    const float* b1  = (const float*)d_in[11];
    const float* g1  = (const float*)d_in[12];
    const float* be1 = (const float*)d_in[13];
    const float* m1  = (const float*)d_in[14];
    const float* v1  = (const float*)d_in[15];
    const float* W2  = (const float*)d_in[16];
    const float* b2  = (const float*)d_in[17];
    const float* g2  = (const float*)d_in[18];
    const float* be2 = (const float*)d_in[19];
    const float* m2  = (const float*)d_in[20];
    const float* v2  = (const float*)d_in[21];
    const float* tW1 = (const float*)d_in[22];
    const float* tb1 = (const float*)d_in[23];
    const float* tW2 = (const float*)d_in[24];
    const float* tb2 = (const float*)d_in[25];
    const float* iW  = (const float*)d_in[26];
    const float* ib  = (const float*)d_in[27];
    const float* ilg = (const float*)d_in[28];
    const float* ilb = (const float*)d_in[29];
    const float* fW1 = (const float*)d_in[30];
    const float* fb1 = (const float*)d_in[31];
    const float* l1g = (const float*)d_in[32];
    const float* l1b = (const float*)d_in[33];
    const float* fW2 = (const float*)d_in[34];
    const float* fb2 = (const float*)d_in[35];
    const float* l2g = (const float*)d_in[36];
    const float* l2b = (const float*)d_in[37];
    const float* fW3 = (const float*)d_in[38];
    const float* fb3 = (const float*)d_in[39];
    float* out = (float*)d_out;

    const int N = in_sizes[0] / 9;
    const int E = in_sizes[1] / 2;
    const int B = in_sizes[6];

    // workspace: h [ENC,N,128], z [ENC,N,128], z2 [ENC,N,256], emb [3,B,128]
    const size_t need3 = ((size_t)3 * N * 512 + (size_t)3 * B * HID) * sizeof(float);
    const int ENC = (ws_size >= need3) ? 3 : 1;  // batch all encoders if ws allows
    float* w = (float*)d_ws;
    const size_t hS = (size_t)N * HID;
    float* hbuf  = w;
    float* zbuf  = hbuf + (size_t)ENC * hS;
    float* z2buf = zbuf + (size_t)ENC * hS;
    float* emb   = z2buf + (size_t)ENC * (size_t)N * 256;

    for (int e0 = 0; e0 < 3; e0 += ENC) {
        dim3 ga((N * HID + 255) / 256, 1, ENC);
        atom_kernel<<<ga, 256, 0, stream>>>(dx, sx, aW, ab, eps, hbuf, zbuf, N, e0);
        for (int l = 0; l < NLAYER; l++) {
            dim3 gs((int)(((size_t)E * 32 + 255) / 256), 1, ENC);
            scatter_kernel<<<gs, 256, 0, stream>>>(de, se, hbuf, zbuf, N, E, e0);
            dim3 gd1((N + 63) / 64, 256 / 64, ENC);
            gemm_bn_relu<128><<<gd1, 256, 0, stream>>>(zbuf, W1, b1, g1, be1, m1, v1,
                                                       z2buf, nullptr, eps, N, 256, l, e0, 0);
            dim3 gd2((N + 63) / 64, 128 / 64, ENC);
            gemm_bn_relu<256><<<gd2, 256, 0, stream>>>(z2buf, W2, b2, g2, be2, m2, v2,
                                                       hbuf, zbuf, eps, N, 128, l, e0,
                                                       (l < NLAYER - 1) ? 1 : 0);
        }
        dim3 gp(B, 1, ENC);
        pool_kernel<<<gp, 128, 0, stream>>>(db, sb, hbuf, emb, N, B, e0);
    }
    fusion_kernel<<<B, 128, 0, stream>>>(emb, t, tW1, tb1, tW2, tb2,
                                         iW, ib, ilg, ilb, fW1, fb1, l1g, l1b,
                                         fW2, fb2, l2g, l2b, fW3, fb3, out, B);
}

// Round 2
// 2329.792 us; speedup vs baseline: 5.8406x; 5.8406x over previous
//
#include <hip/hip_runtime.h>

#define HID 128
#define NLAYER 4
#define SCAN_T 1024

// ---------------------------------------------------------------------------
// lower_bound on sorted int array
// ---------------------------------------------------------------------------
__device__ __forceinline__ int lowbound(const int* __restrict__ a, int n, int v) {
    int lo = 0, hi = n;
    while (lo < hi) {
        int mid = (lo + hi) >> 1;
        if (a[mid] < v) lo = mid + 1; else hi = mid;
    }
    return lo;
}

// ---------------------------------------------------------------------------
// CSR build: histogram of dst, exclusive scan, bucket fill (int atomics only)
// ---------------------------------------------------------------------------
__global__ void hist_kernel(const int* __restrict__ ei, int* __restrict__ cnt, int E) {
    int e = blockIdx.x * blockDim.x + threadIdx.x;
    if (e < E) atomicAdd(&cnt[ei[E + e]], 1);
}

__global__ __launch_bounds__(SCAN_T) void scan_kernel(const int* __restrict__ cnt,
                                                      int* __restrict__ rowptr, int N) {
    __shared__ int part[SCAN_T];
    const int tid = threadIdx.x;
    const int chunk = (N + SCAN_T - 1) / SCAN_T;
    const int lo = tid * chunk;
    const int hi = min(lo + chunk, N);
    int s = 0;
    for (int i = lo; i < hi; i++) s += cnt[i];
    part[tid] = s;
    __syncthreads();
    for (int o = 1; o < SCAN_T; o <<= 1) {
        int v = (tid >= o) ? part[tid - o] : 0;
        __syncthreads();
        part[tid] += v;
        __syncthreads();
    }
    int ex = (tid == 0) ? 0 : part[tid - 1];
    for (int i = lo; i < hi; i++) { rowptr[i] = ex; ex += cnt[i]; }
    if (tid == SCAN_T - 1) rowptr[N] = ex;
}

__global__ void fill_kernel(const int* __restrict__ ei, const int* __restrict__ rowptr,
                            int* __restrict__ cnt2, int* __restrict__ srcidx, int E) {
    int e = blockIdx.x * blockDim.x + threadIdx.x;
    if (e < E) {
        const int dst = ei[E + e];
        const int pos = rowptr[dst] + atomicAdd(&cnt2[dst], 1);
        srcidx[pos] = ei[e];
    }
}

// ---------------------------------------------------------------------------
// Atom encoder: h = x @ aW + ab
// ---------------------------------------------------------------------------
__global__ void atom_kernel(const float* __restrict__ dx, const float* __restrict__ sx,
                            const float* __restrict__ aW, const float* __restrict__ ab,
                            float* __restrict__ h, int N, int enc0) {
    const int slot = blockIdx.z;
    const int enc  = enc0 + slot;
    long idx = (long)blockIdx.x * blockDim.x + threadIdx.x;
    if (idx >= (long)N * HID) return;
    const int n = (int)(idx / HID), c = (int)(idx % HID);
    const float* x = (enc < 2) ? dx : sx;
    const float* W = aW + (size_t)enc * 9 * HID;
    float acc = ab[enc * HID + c];
#pragma unroll
    for (int k = 0; k < 9; k++) acc = fmaf(x[n * 9 + k], W[k * HID + c], acc);
    h[(size_t)slot * N * HID + idx] = acc;
}

// ---------------------------------------------------------------------------
// Gather-aggregate (replaces atomic scatter):
//   z[n] = (1+eps[enc][l]) * h[n] + sum_{e: dst(e)=n} h[src(e)]
// 32 lanes per node (float4/lane), 8 nodes per 256-thread block.
// ---------------------------------------------------------------------------
__global__ __launch_bounds__(256) void gather_agg(
    const int* __restrict__ rpd, const int* __restrict__ sid,
    const int* __restrict__ rps, const int* __restrict__ sis,
    const float* __restrict__ h, float* __restrict__ z,
    const float* __restrict__ eps, int N, int enc0, int l) {
    const int slot = blockIdx.z;
    const int enc  = enc0 + slot;
    const int node = blockIdx.x * 8 + (threadIdx.x >> 5);
    if (node >= N) return;
    const int lane = threadIdx.x & 31;
    const int* rowptr = (enc < 2) ? rpd : rps;
    const int* srcidx = (enc < 2) ? sid : sis;
    const int lo = rowptr[node], hi = rowptr[node + 1];
    const float* hp = h + (size_t)slot * N * HID;
    float4 s = *(const float4*)&hp[(size_t)node * HID + lane * 4];
    const float scale = 1.f + eps[enc * NLAYER + l];
    s.x *= scale; s.y *= scale; s.z *= scale; s.w *= scale;
    for (int j = lo; j < hi; j++) {
        const int src = srcidx[j];
        const float4 v = *(const float4*)&hp[(size_t)src * HID + lane * 4];
        s.x += v.x; s.y += v.y; s.z += v.z; s.w += v.w;
    }
    *(float4*)&z[(size_t)slot * N * HID + (size_t)node * HID + lane * 4] = s;
}

// ---------------------------------------------------------------------------
// GEMM + bias + BN + ReLU epilogue.  out = relu((A@W + bias - m)*g/sqrt(v+1e-5) + b)
// A: [M, KDIM] row-major (per-slot stride M*KDIM). W: [3][L][KDIM][Nout].
// Tile 64x64, K-chunk 16, 256 threads, 4x4 micro-tile.
// ---------------------------------------------------------------------------
template <int KDIM>
__global__ __launch_bounds__(256) void gemm_bn_relu(
    const float* __restrict__ A, const float* __restrict__ Wt,
    const float* __restrict__ bias,
    const float* __restrict__ bng, const float* __restrict__ bnb,
    const float* __restrict__ bnm, const float* __restrict__ bnv,
    float* __restrict__ out,
    int M, int Nout, int l, int enc0) {
    const int slot = blockIdx.z;
    const int enc  = enc0 + slot;
    const float* Ap = A + (size_t)slot * M * KDIM;
    const float* Wp = Wt + ((size_t)enc * NLAYER + l) * (size_t)KDIM * Nout;
    const size_t poff = ((size_t)enc * NLAYER + l) * (size_t)Nout;

    __shared__ float As[16][68];  // [k][m], padded
    __shared__ float Bs[16][64];  // [k][n]
    const int tid = threadIdx.x;
    const int tx = tid & 15, ty = tid >> 4;
    const int m0 = blockIdx.x * 64, n0 = blockIdx.y * 64;

    float acc[4][4] = {{0.f}};

    for (int k0 = 0; k0 < KDIM; k0 += 16) {
        __syncthreads();
        {   // A tile: 64 rows x 16 k, each thread one float4
            const int row = tid >> 2, c4 = (tid & 3) * 4;
            const int gr = m0 + row;
            float4 av = make_float4(0.f, 0.f, 0.f, 0.f);
            if (gr < M) av = *(const float4*)&Ap[(size_t)gr * KDIM + k0 + c4];
            As[c4 + 0][row] = av.x;
            As[c4 + 1][row] = av.y;
            As[c4 + 2][row] = av.z;
            As[c4 + 3][row] = av.w;
        }
        {   // B tile: 16 k x 64 n
            const int n = tid & 63;
#pragma unroll
            for (int i = 0; i < 4; i++) {
                const int kk = (tid >> 6) + i * 4;
                Bs[kk][n] = Wp[(size_t)(k0 + kk) * Nout + n0 + n];
            }
        }
        __syncthreads();
#pragma unroll
        for (int kk = 0; kk < 16; kk++) {
            float4 a4 = *(const float4*)&As[kk][ty * 4];
            float4 b4 = *(const float4*)&Bs[kk][tx * 4];
            float a[4] = {a4.x, a4.y, a4.z, a4.w};
            float b[4] = {b4.x, b4.y, b4.z, b4.w};
#pragma unroll
            for (int i = 0; i < 4; i++)
#pragma unroll
                for (int j = 0; j < 4; j++) acc[i][j] = fmaf(a[i], b[j], acc[i][j]);
        }
    }

    const int c0 = n0 + tx * 4;
    float4 f_b  = *(const float4*)&bias[poff + c0];
    float4 f_g  = *(const float4*)&bng[poff + c0];
    float4 f_be = *(const float4*)&bnb[poff + c0];
    float4 f_m  = *(const float4*)&bnm[poff + c0];
    float4 f_v  = *(const float4*)&bnv[poff + c0];
    float sc[4], sh[4];
    {
        float bb[4] = {f_b.x, f_b.y, f_b.z, f_b.w};
        float gg[4] = {f_g.x, f_g.y, f_g.z, f_g.w};
        float be[4] = {f_be.x, f_be.y, f_be.z, f_be.w};
        float mm[4] = {f_m.x, f_m.y, f_m.z, f_m.w};
        float vv[4] = {f_v.x, f_v.y, f_v.z, f_v.w};
#pragma unroll
        for (int j = 0; j < 4; j++) {
            sc[j] = gg[j] * rsqrtf(vv[j] + 1e-5f);
            sh[j] = (bb[j] - mm[j]) * sc[j] + be[j];
        }
    }
    float* outp = out + (size_t)slot * M * Nout;
#pragma unroll
    for (int i = 0; i < 4; i++) {
        const int gr = m0 + ty * 4 + i;
        if (gr >= M) continue;
        float o[4];
#pragma unroll
        for (int j = 0; j < 4; j++) o[j] = fmaxf(fmaf(acc[i][j], sc[j], sh[j]), 0.f);
        *(float4*)&outp[(size_t)gr * Nout + c0] = make_float4(o[0], o[1], o[2], o[3]);
    }
}

// ---------------------------------------------------------------------------
// Segment-mean pool (bat sorted -> contiguous ranges)
// ---------------------------------------------------------------------------
__global__ __launch_bounds__(128) void pool_kernel(const int* __restrict__ db,
                                                   const int* __restrict__ sb,
                                                   const float* __restrict__ h,
                                                   float* __restrict__ emb,
                                                   int N, int B, int enc0) {
    const int slot = blockIdx.z;
    const int enc  = enc0 + slot;
    const int* bat = (enc < 2) ? db : sb;
    const int g = blockIdx.x;
    const int lo = lowbound(bat, N, g);
    const int hi = lowbound(bat, N, g + 1);
    const int c = threadIdx.x;
    float s = 0.f;
    const float* hp = h + (size_t)slot * N * HID;
    for (int n = lo; n < hi; n++) s += hp[(size_t)n * HID + c];
    const float cnt = (float)(hi - lo);
    emb[((size_t)enc * B + g) * HID + c] = s / fmaxf(cnt, 1.f);
}

// ---------------------------------------------------------------------------
__device__ __forceinline__ float block_sum128(float x, float* red, int tid) {
    red[tid] = x;
    __syncthreads();
    if (tid < 64) {
        float v = red[tid] + red[tid + 64];
#pragma unroll
        for (int o = 32; o > 0; o >>= 1) v += __shfl_down(v, o);
        if (tid == 0) red[0] = v;
    }
    __syncthreads();
    float r = red[0];
    __syncthreads();
    return r;
}

// ---------------------------------------------------------------------------
// Fusion head (unchanged)
// ---------------------------------------------------------------------------
__global__ __launch_bounds__(128) void fusion_kernel(
    const float* __restrict__ emb, const float* __restrict__ t,
    const float* __restrict__ tW1, const float* __restrict__ tb1,
    const float* __restrict__ tW2, const float* __restrict__ tb2,
    const float* __restrict__ iW, const float* __restrict__ ib,
    const float* __restrict__ ilg, const float* __restrict__ ilb,
    const float* __restrict__ fW1, const float* __restrict__ fb1,
    const float* __restrict__ l1g, const float* __restrict__ l1b,
    const float* __restrict__ fW2, const float* __restrict__ fb2,
    const float* __restrict__ l2g, const float* __restrict__ l2b,
    const float* __restrict__ fW3, const float* __restrict__ fb3,
    float* __restrict__ out, int B) {
    const int r = blockIdx.x;
    const int tid = threadIdx.x;
    __shared__ float cs[256];
    __shared__ float cat[288];
    __shared__ float buf[128];
    __shared__ float red[128];
    __shared__ float tmp32[32];

    cs[tid]        = emb[((size_t)1 * B + r) * HID + tid];
    cs[128 + tid]  = emb[((size_t)2 * B + r) * HID + tid];
    cat[tid]       = emb[((size_t)0 * B + r) * HID + tid];
    __syncthreads();

    float acc = ib[tid];
    for (int k = 0; k < 256; k++) acc = fmaf(cs[k], iW[k * HID + tid], acc);
    float mu  = block_sum128(acc, red, tid) * (1.f / 128.f);
    float d   = acc - mu;
    float var = block_sum128(d * d, red, tid) * (1.f / 128.f);
    float inter = fmaxf(d * rsqrtf(var + 1e-5f) * ilg[tid] + ilb[tid], 0.f);
    cat[128 + tid] = inter;

    if (tid < 32) tmp32[tid] = fmaxf(fmaf(t[r], tW1[tid], tb1[tid]), 0.f);
    __syncthreads();
    if (tid < 32) {
        float a2 = tb2[tid];
        for (int j = 0; j < 32; j++) a2 = fmaf(tmp32[j], tW2[j * 32 + tid], a2);
        cat[256 + tid] = a2;
    }
    __syncthreads();

    float a1 = fb1[tid];
    for (int k = 0; k < 288; k++) a1 = fmaf(cat[k], fW1[k * HID + tid], a1);
    mu  = block_sum128(a1, red, tid) * (1.f / 128.f);
    d   = a1 - mu;
    var = block_sum128(d * d, red, tid) * (1.f / 128.f);
    buf[tid] = fmaxf(d * rsqrtf(var + 1e-5f) * l1g[tid] + l1b[tid], 0.f);
    __syncthreads();

    float a2v = 0.f;
    if (tid < 64) {
        a2v = fb2[tid];
        for (int k = 0; k < 128; k++) a2v = fmaf(buf[k], fW2[k * 64 + tid], a2v);
    }
    mu = block_sum128((tid < 64) ? a2v : 0.f, red, tid) * (1.f / 64.f);
    float d2 = (tid < 64) ? (a2v - mu) : 0.f;
    var = block_sum128(d2 * d2, red, tid) * (1.f / 64.f);
    float contrib = 0.f;
    if (tid < 64) {
        float h2 = fmaxf(d2 * rsqrtf(var + 1e-5f) * l2g[tid] + l2b[tid], 0.f);
        contrib = h2 * fW3[tid];
    }
    float s = block_sum128(contrib, red, tid);
    if (tid == 0) out[r] = s + fb3[0];
}

// ---------------------------------------------------------------------------
extern "C" void kernel_launch(void* const* d_in, const int* in_sizes, int n_in,
                              void* d_out, int out_size, void* d_ws, size_t ws_size,
                              hipStream_t stream) {
    const float* dx  = (const float*)d_in[0];
    const int*   de  = (const int*)d_in[1];
    const int*   db  = (const int*)d_in[2];
    const float* sx  = (const float*)d_in[3];
    const int*   se  = (const int*)d_in[4];
    const int*   sb  = (const int*)d_in[5];
    const float* t   = (const float*)d_in[6];
    const float* aW  = (const float*)d_in[7];
    const float* ab  = (const float*)d_in[8];
    const float* eps = (const float*)d_in[9];
    const float* W1  = (const float*)d_in[10];
    const float* b1  = (const float*)d_in[11];
    const float* g1  = (const float*)d_in[12];
    const float* be1 = (const float*)d_in[13];
    const float* m1  = (const float*)d_in[14];
    const float* v1  = (const float*)d_in[15];
    const float* W2  = (const float*)d_in[16];
    const float* b2  = (const float*)d_in[17];
    const float* g2  = (const float*)d_in[18];
    const float* be2 = (const float*)d_in[19];
    const float* m2  = (const float*)d_in[20];
    const float* v2  = (const float*)d_in[21];
    const float* tW1 = (const float*)d_in[22];
    const float* tb1 = (const float*)d_in[23];
    const float* tW2 = (const float*)d_in[24];
    const float* tb2 = (const float*)d_in[25];
    const float* iW  = (const float*)d_in[26];
    const float* ib  = (const float*)d_in[27];
    const float* ilg = (const float*)d_in[28];
    const float* ilb = (const float*)d_in[29];
    const float* fW1 = (const float*)d_in[30];
    const float* fb1 = (const float*)d_in[31];
    const float* l1g = (const float*)d_in[32];
    const float* l1b = (const float*)d_in[33];
    const float* fW2 = (const float*)d_in[34];
    const float* fb2 = (const float*)d_in[35];
    const float* l2g = (const float*)d_in[36];
    const float* l2b = (const float*)d_in[37];
    const float* fW3 = (const float*)d_in[38];
    const float* fb3 = (const float*)d_in[39];
    float* out = (float*)d_out;

    const int N  = in_sizes[0] / 9;
    const int Ed = in_sizes[1] / 2;
    const int Es = in_sizes[4] / 2;
    const int B  = in_sizes[6];

    // ---- workspace layout ----
    // ints: rpd[N+1] rps[N+1] cntd[N] cnts[N] cnt2d[N] cnt2s[N] sid[Ed] sis[Es]
    char* w8 = (char*)d_ws;
    int* rpd   = (int*)w8;
    int* rps   = rpd + (N + 1);
    int* cntd  = rps + (N + 1);
    int* cnts  = cntd + N;
    int* cnt2d = cnts + N;
    int* cnt2s = cnt2d + N;
    int* sid   = cnt2s + N;
    int* sis   = sid + Ed;
    size_t int_bytes = ((char*)(sis + Es)) - w8;
    size_t foff = (int_bytes + 255) & ~(size_t)255;  // align floats

    float* fbase = (float*)(w8 + foff);
    const size_t hS = (size_t)N * HID;
    const size_t fixed = (size_t)3 * B * HID;  // emb
    const size_t need3 = foff + (fixed + 3 * N * 512) * sizeof(float);
    const int ENC = (ws_size >= need3) ? 3 : 1;

    float* emb   = fbase;
    float* hbuf  = emb + fixed;
    float* zbuf  = hbuf + (size_t)ENC * hS;
    float* z2buf = zbuf + (size_t)ENC * hS;

    // ---- CSR build (both graph types) ----
    hipMemsetAsync(cntd, 0, (size_t)4 * N * sizeof(int), stream);  // cntd,cnts,cnt2d,cnt2s
    hist_kernel<<<(Ed + 255) / 256, 256, 0, stream>>>(de, cntd, Ed);
    hist_kernel<<<(Es + 255) / 256, 256, 0, stream>>>(se, cnts, Es);
    scan_kernel<<<1, SCAN_T, 0, stream>>>(cntd, rpd, N);
    scan_kernel<<<1, SCAN_T, 0, stream>>>(cnts, rps, N);
    fill_kernel<<<(Ed + 255) / 256, 256, 0, stream>>>(de, rpd, cnt2d, sid, Ed);
    fill_kernel<<<(Es + 255) / 256, 256, 0, stream>>>(se, rps, cnt2s, sis, Es);

    // ---- encoders ----
    for (int e0 = 0; e0 < 3; e0 += ENC) {
        dim3 ga((N * HID + 255) / 256, 1, ENC);
        atom_kernel<<<ga, 256, 0, stream>>>(dx, sx, aW, ab, hbuf, N, e0);
        for (int l = 0; l < NLAYER; l++) {
            dim3 gg((N + 7) / 8, 1, ENC);
            gather_agg<<<gg, 256, 0, stream>>>(rpd, sid, rps, sis, hbuf, zbuf, eps, N, e0, l);
            dim3 gd1((N + 63) / 64, 256 / 64, ENC);
            gemm_bn_relu<128><<<gd1, 256, 0, stream>>>(zbuf, W1, b1, g1, be1, m1, v1,
                                                       z2buf, N, 256, l, e0);
            dim3 gd2((N + 63) / 64, 128 / 64, ENC);
            gemm_bn_relu<256><<<gd2, 256, 0, stream>>>(z2buf, W2, b2, g2, be2, m2, v2,
                                                       hbuf, N, 128, l, e0);
        }
        dim3 gp(B, 1, ENC);
        pool_kernel<<<gp, 128, 0, stream>>>(db, sb, hbuf, emb, N, B, e0);
    }
    fusion_kernel<<<B, 128, 0, stream>>>(emb, t, tW1, tb1, tW2, tb2,
                                         iW, ib, ilg, ilb, fW1, fb1, l1g, l1b,
                                         fW2, fb2, l2g, l2b, fW3, fb3, out, B);
}

// Round 3
// 1194.828 us; speedup vs baseline: 11.3886x; 1.9499x over previous
//
#include <hip/hip_runtime.h>

#define HID 128
#define NLAYER 4

typedef unsigned short u16;
typedef __attribute__((ext_vector_type(4))) unsigned short u16x4;
typedef __attribute__((ext_vector_type(8))) short short8;
typedef __attribute__((ext_vector_type(4))) float floatx4;

__device__ __forceinline__ float bf2f(u16 u) {
    union { unsigned int i; float f; } v; v.i = ((unsigned int)u) << 16; return v.f;
}
__device__ __forceinline__ u16 f2bf(float f) {
    union { float f; unsigned int i; } v; v.f = f;
    unsigned int r = v.i + 0x7FFFu + ((v.i >> 16) & 1u);
    return (u16)(r >> 16);
}

// ---------------------------------------------------------------------------
__device__ __forceinline__ int lowbound(const int* __restrict__ a, int n, int v) {
    int lo = 0, hi = n;
    while (lo < hi) {
        int mid = (lo + hi) >> 1;
        if (a[mid] < v) lo = mid + 1; else hi = mid;
    }
    return lo;
}

// ---------------------------------------------------------------------------
// Weight prep: fp32 -> bf16, transposed to [enc][l][n][k].
// W1: [3][4][128][256] -> W1t [3][4][256][128]; W2: [3][4][256][128] -> W2t [3][4][128][256]
// ---------------------------------------------------------------------------
__global__ void prep_weights(const float* __restrict__ W1, const float* __restrict__ W2,
                             u16* __restrict__ W1t, u16* __restrict__ W2t) {
    const int T = 3 * NLAYER * 128 * 256;  // 393216
    int o = blockIdx.x * blockDim.x + threadIdx.x;
    if (o < T) {
        int k = o & 127, n = (o >> 7) & 255, el = o >> 15;
        W1t[o] = f2bf(W1[((size_t)el * 128 + k) * 256 + n]);
    } else if (o < 2 * T) {
        int o2 = o - T;
        int k = o2 & 255, n = (o2 >> 8) & 127, el = o2 >> 15;
        W2t[o2] = f2bf(W2[((size_t)el * 256 + k) * 128 + n]);
    }
}

// ---------------------------------------------------------------------------
// CSR build: histogram (int atomics), 3-phase parallel scan, bucket fill
// ---------------------------------------------------------------------------
__global__ void hist_kernel(const int* __restrict__ ei, int* __restrict__ cnt, int E) {
    int e = blockIdx.x * blockDim.x + threadIdx.x;
    if (e < E) atomicAdd(&cnt[ei[E + e]], 1);
}

__global__ __launch_bounds__(256) void scan1(const int* __restrict__ cnt,
                                             int* __restrict__ bsum, int N) {
    __shared__ int s[256];
    int i = blockIdx.x * 256 + threadIdx.x;
    s[threadIdx.x] = (i < N) ? cnt[i] : 0;
    __syncthreads();
    for (int o = 128; o > 0; o >>= 1) {
        if (threadIdx.x < o) s[threadIdx.x] += s[threadIdx.x + o];
        __syncthreads();
    }
    if (threadIdx.x == 0) bsum[blockIdx.x] = s[0];
}

__global__ __launch_bounds__(256) void scan2(int* __restrict__ bsum, int nb) {
    __shared__ int s[256];
    __shared__ int carry;
    if (threadIdx.x == 0) carry = 0;
    __syncthreads();
    for (int base = 0; base < nb; base += 256) {
        int i = base + threadIdx.x;
        int v = (i < nb) ? bsum[i] : 0;
        s[threadIdx.x] = v;
        __syncthreads();
        for (int o = 1; o < 256; o <<= 1) {
            int tv = (threadIdx.x >= o) ? s[threadIdx.x - o] : 0;
            __syncthreads();
            s[threadIdx.x] += tv;
            __syncthreads();
        }
        int excl = carry + s[threadIdx.x] - v;
        if (i < nb) bsum[i] = excl;
        __syncthreads();
        if (threadIdx.x == 0) carry += s[255];
        __syncthreads();
    }
}

__global__ __launch_bounds__(256) void scan3(const int* __restrict__ cnt,
                                             const int* __restrict__ bsum,
                                             int* __restrict__ rowptr, int N, int E) {
    __shared__ int s[256];
    int i = blockIdx.x * 256 + threadIdx.x;
    int v = (i < N) ? cnt[i] : 0;
    s[threadIdx.x] = v;
    __syncthreads();
    for (int o = 1; o < 256; o <<= 1) {
        int tv = (threadIdx.x >= o) ? s[threadIdx.x - o] : 0;
        __syncthreads();
        s[threadIdx.x] += tv;
        __syncthreads();
    }
    if (i < N) rowptr[i] = bsum[blockIdx.x] + s[threadIdx.x] - v;
    if (i == 0 && blockIdx.x == 0) rowptr[N] = E;
}

__global__ void fill_kernel(const int* __restrict__ ei, const int* __restrict__ rowptr,
                            int* __restrict__ cnt2, int* __restrict__ srcidx, int E) {
    int e = blockIdx.x * blockDim.x + threadIdx.x;
    if (e < E) {
        const int dst = ei[E + e];
        const int pos = rowptr[dst] + atomicAdd(&cnt2[dst], 1);
        srcidx[pos] = ei[e];
    }
}

// ---------------------------------------------------------------------------
// Atom encoder: h = x @ aW + ab  (fp32 compute, bf16 store)
// ---------------------------------------------------------------------------
__global__ void atom_kernel(const float* __restrict__ dx, const float* __restrict__ sx,
                            const float* __restrict__ aW, const float* __restrict__ ab,
                            u16* __restrict__ h, int N, int enc0) {
    const int slot = blockIdx.z;
    const int enc  = enc0 + slot;
    long idx = (long)blockIdx.x * blockDim.x + threadIdx.x;
    if (idx >= (long)N * HID) return;
    const int n = (int)(idx / HID), c = (int)(idx % HID);
    const float* x = (enc < 2) ? dx : sx;
    const float* W = aW + (size_t)enc * 9 * HID;
    float acc = ab[enc * HID + c];
#pragma unroll
    for (int k = 0; k < 9; k++) acc = fmaf(x[n * 9 + k], W[k * HID + c], acc);
    h[(size_t)slot * N * HID + idx] = f2bf(acc);
}

// ---------------------------------------------------------------------------
// Gather-aggregate: z[n] = (1+eps)*h[n] + sum_{src->n} h[src]   (bf16 io, fp32 acc)
// ---------------------------------------------------------------------------
__global__ __launch_bounds__(256) void gather_agg(
    const int* __restrict__ rpd, const int* __restrict__ sid,
    const int* __restrict__ rps, const int* __restrict__ sis,
    const u16* __restrict__ h, u16* __restrict__ z,
    const float* __restrict__ eps, int N, int enc0, int l) {
    const int slot = blockIdx.z;
    const int enc  = enc0 + slot;
    const int node = blockIdx.x * 8 + (threadIdx.x >> 5);
    if (node >= N) return;
    const int lane = threadIdx.x & 31;
    const int* rowptr = (enc < 2) ? rpd : rps;
    const int* srcidx = (enc < 2) ? sid : sis;
    const int lo = rowptr[node], hi = rowptr[node + 1];
    const u16* hp = h + (size_t)slot * N * HID;
    const int coff = lane * 4;
    u16x4 hv = *(const u16x4*)(hp + (size_t)node * HID + coff);
    const float scale = 1.f + eps[enc * NLAYER + l];
    float s0 = bf2f(hv.x) * scale, s1 = bf2f(hv.y) * scale;
    float s2 = bf2f(hv.z) * scale, s3 = bf2f(hv.w) * scale;
    for (int j = lo; j < hi; j++) {
        const int src = srcidx[j];
        u16x4 v = *(const u16x4*)(hp + (size_t)src * HID + coff);
        s0 += bf2f(v.x); s1 += bf2f(v.y); s2 += bf2f(v.z); s3 += bf2f(v.w);
    }
    u16x4 o;
    o.x = f2bf(s0); o.y = f2bf(s1); o.z = f2bf(s2); o.w = f2bf(s3);
    *(u16x4*)(z + (size_t)slot * N * HID + (size_t)node * HID + coff) = o;
}

// ---------------------------------------------------------------------------
// MFMA GEMM (bf16 in, fp32 acc, fused bias+BN+ReLU, bf16 out)
// A: [slot][M][K].  Wt: [enc][l][Nout][K] (n-major).  Block 256 thr, tile 128x128, BK=64.
// LDS rows padded to 72 elems (144 B): frag ds_read_b128 <=2-way conflicts (free, m136).
// MFMA 16x16x32 bf16; C/D: col=lane&15, row=(lane>>4)*4+reg  [m89-verified].
// ---------------------------------------------------------------------------
template <int K>
__global__ __launch_bounds__(256) void gemm_mfma(
    const u16* __restrict__ A, const u16* __restrict__ Wt,
    const float* __restrict__ bias,
    const float* __restrict__ bng, const float* __restrict__ bnb,
    const float* __restrict__ bnm, const float* __restrict__ bnv,
    u16* __restrict__ out, int M, int Nout, int l, int enc0) {
    const int slot = blockIdx.z;
    const int enc  = enc0 + slot;
    const int m0 = blockIdx.x * 128, n0 = blockIdx.y * 128;
    const u16* Ap = A + (size_t)slot * M * K;
    const u16* Wp = Wt + ((size_t)(enc * NLAYER + l) * Nout + n0) * K;

    __shared__ u16 As[128 * 72];
    __shared__ u16 Bs[128 * 72];

    const int tid = threadIdx.x;
    const int lane = tid & 63, w = tid >> 6;
    const int wr = w & 1, wc = w >> 1;
    const int srow = tid >> 3, sc8 = tid & 7;

    floatx4 acc[4][4];
#pragma unroll
    for (int i = 0; i < 4; i++)
#pragma unroll
        for (int j = 0; j < 4; j++) acc[i][j] = (floatx4)0.f;

    for (int k0 = 0; k0 < K; k0 += 64) {
#pragma unroll
        for (int p = 0; p < 4; p++) {
            const int row = p * 32 + srow;
            int gr = m0 + row; if (gr >= M) gr = M - 1;
            uint4 va = *(const uint4*)(Ap + (size_t)gr * K + k0 + sc8 * 8);
            *(uint4*)&As[row * 72 + sc8 * 8] = va;
            uint4 vb = *(const uint4*)(Wp + (size_t)row * K + k0 + sc8 * 8);
            *(uint4*)&Bs[row * 72 + sc8 * 8] = vb;
        }
        __syncthreads();
#pragma unroll
        for (int s = 0; s < 2; s++) {
            const int k8 = s * 4 + (lane >> 4);
            short8 av[4], bv[4];
#pragma unroll
            for (int mi = 0; mi < 4; mi++) {
                const int row = wr * 64 + mi * 16 + (lane & 15);
                av[mi] = *(const short8*)&As[row * 72 + k8 * 8];
            }
#pragma unroll
            for (int ni = 0; ni < 4; ni++) {
                const int row = wc * 64 + ni * 16 + (lane & 15);
                bv[ni] = *(const short8*)&Bs[row * 72 + k8 * 8];
            }
#pragma unroll
            for (int mi = 0; mi < 4; mi++)
#pragma unroll
                for (int ni = 0; ni < 4; ni++)
                    acc[mi][ni] = __builtin_amdgcn_mfma_f32_16x16x32_bf16(
                        av[mi], bv[ni], acc[mi][ni], 0, 0, 0);
        }
        __syncthreads();
    }

    const size_t poff = (size_t)(enc * NLAYER + l) * Nout;
    u16* outp = out + (size_t)slot * M * Nout;
#pragma unroll
    for (int ni = 0; ni < 4; ni++) {
        const int col = n0 + wc * 64 + ni * 16 + (lane & 15);
        const float sc = bng[poff + col] * rsqrtf(bnv[poff + col] + 1e-5f);
        const float sh = (bias[poff + col] - bnm[poff + col]) * sc + bnb[poff + col];
#pragma unroll
        for (int mi = 0; mi < 4; mi++) {
#pragma unroll
            for (int r = 0; r < 4; r++) {
                const int gr = m0 + wr * 64 + mi * 16 + (lane >> 4) * 4 + r;
                if (gr < M)
                    outp[(size_t)gr * Nout + col] = f2bf(fmaxf(fmaf(acc[mi][ni][r], sc, sh), 0.f));
            }
        }
    }
}

// ---------------------------------------------------------------------------
// Segment-mean pool (bat sorted). bf16 in, fp32 out.
// ---------------------------------------------------------------------------
__global__ __launch_bounds__(128) void pool_kernel(const int* __restrict__ db,
                                                   const int* __restrict__ sb,
                                                   const u16* __restrict__ h,
                                                   float* __restrict__ emb,
                                                   int N, int B, int enc0) {
    const int slot = blockIdx.z;
    const int enc  = enc0 + slot;
    const int* bat = (enc < 2) ? db : sb;
    const int g = blockIdx.x;
    const int lo = lowbound(bat, N, g);
    const int hi = lowbound(bat, N, g + 1);
    const int c = threadIdx.x;
    float s = 0.f;
    const u16* hp = h + (size_t)slot * N * HID;
    for (int n = lo; n < hi; n++) s += bf2f(hp[(size_t)n * HID + c]);
    const float cnt = (float)(hi - lo);
    emb[((size_t)enc * B + g) * HID + c] = s / fmaxf(cnt, 1.f);
}

// ---------------------------------------------------------------------------
__device__ __forceinline__ float block_sum128(float x, float* red, int tid) {
    red[tid] = x;
    __syncthreads();
    if (tid < 64) {
        float v = red[tid] + red[tid + 64];
#pragma unroll
        for (int o = 32; o > 0; o >>= 1) v += __shfl_down(v, o);
        if (tid == 0) red[0] = v;
    }
    __syncthreads();
    float r = red[0];
    __syncthreads();
    return r;
}

// ---------------------------------------------------------------------------
// Fusion head (fp32)
// ---------------------------------------------------------------------------
__global__ __launch_bounds__(128) void fusion_kernel(
    const float* __restrict__ emb, const float* __restrict__ t,
    const float* __restrict__ tW1, const float* __restrict__ tb1,
    const float* __restrict__ tW2, const float* __restrict__ tb2,
    const float* __restrict__ iW, const float* __restrict__ ib,
    const float* __restrict__ ilg, const float* __restrict__ ilb,
    const float* __restrict__ fW1, const float* __restrict__ fb1,
    const float* __restrict__ l1g, const float* __restrict__ l1b,
    const float* __restrict__ fW2, const float* __restrict__ fb2,
    const float* __restrict__ l2g, const float* __restrict__ l2b,
    const float* __restrict__ fW3, const float* __restrict__ fb3,
    float* __restrict__ out, int B) {
    const int r = blockIdx.x;
    const int tid = threadIdx.x;
    __shared__ float cs[256];
    __shared__ float cat[288];
    __shared__ float buf[128];
    __shared__ float red[128];
    __shared__ float tmp32[32];

    cs[tid]        = emb[((size_t)1 * B + r) * HID + tid];
    cs[128 + tid]  = emb[((size_t)2 * B + r) * HID + tid];
    cat[tid]       = emb[((size_t)0 * B + r) * HID + tid];
    __syncthreads();

    float acc = ib[tid];
    for (int k = 0; k < 256; k++) acc = fmaf(cs[k], iW[k * HID + tid], acc);
    float mu  = block_sum128(acc, red, tid) * (1.f / 128.f);
    float d   = acc - mu;
    float var = block_sum128(d * d, red, tid) * (1.f / 128.f);
    float inter = fmaxf(d * rsqrtf(var + 1e-5f) * ilg[tid] + ilb[tid], 0.f);
    cat[128 + tid] = inter;

    if (tid < 32) tmp32[tid] = fmaxf(fmaf(t[r], tW1[tid], tb1[tid]), 0.f);
    __syncthreads();
    if (tid < 32) {
        float a2 = tb2[tid];
        for (int j = 0; j < 32; j++) a2 = fmaf(tmp32[j], tW2[j * 32 + tid], a2);
        cat[256 + tid] = a2;
    }
    __syncthreads();

    float a1 = fb1[tid];
    for (int k = 0; k < 288; k++) a1 = fmaf(cat[k], fW1[k * HID + tid], a1);
    mu  = block_sum128(a1, red, tid) * (1.f / 128.f);
    d   = a1 - mu;
    var = block_sum128(d * d, red, tid) * (1.f / 128.f);
    buf[tid] = fmaxf(d * rsqrtf(var + 1e-5f) * l1g[tid] + l1b[tid], 0.f);
    __syncthreads();

    float a2v = 0.f;
    if (tid < 64) {
        a2v = fb2[tid];
        for (int k = 0; k < 128; k++) a2v = fmaf(buf[k], fW2[k * 64 + tid], a2v);
    }
    mu = block_sum128((tid < 64) ? a2v : 0.f, red, tid) * (1.f / 64.f);
    float d2 = (tid < 64) ? (a2v - mu) : 0.f;
    var = block_sum128(d2 * d2, red, tid) * (1.f / 64.f);
    float contrib = 0.f;
    if (tid < 64) {
        float h2 = fmaxf(d2 * rsqrtf(var + 1e-5f) * l2g[tid] + l2b[tid], 0.f);
        contrib = h2 * fW3[tid];
    }
    float s = block_sum128(contrib, red, tid);
    if (tid == 0) out[r] = s + fb3[0];
}

// ---------------------------------------------------------------------------
extern "C" void kernel_launch(void* const* d_in, const int* in_sizes, int n_in,
                              void* d_out, int out_size, void* d_ws, size_t ws_size,
                              hipStream_t stream) {
    const float* dx  = (const float*)d_in[0];
    const int*   de  = (const int*)d_in[1];
    const int*   db  = (const int*)d_in[2];
    const float* sx  = (const float*)d_in[3];
    const int*   se  = (const int*)d_in[4];
    const int*   sb  = (const int*)d_in[5];
    const float* t   = (const float*)d_in[6];
    const float* aW  = (const float*)d_in[7];
    const float* ab  = (const float*)d_in[8];
    const float* eps = (const float*)d_in[9];
    const float* W1  = (const float*)d_in[10];
    const float* b1  = (const float*)d_in[11];
    const float* g1  = (const float*)d_in[12];
    const float* be1 = (const float*)d_in[13];
    const float* m1  = (const float*)d_in[14];
    const float* v1  = (const float*)d_in[15];
    const float* W2  = (const float*)d_in[16];
    const float* b2  = (const float*)d_in[17];
    const float* g2  = (const float*)d_in[18];
    const float* be2 = (const float*)d_in[19];
    const float* m2  = (const float*)d_in[20];
    const float* v2  = (const float*)d_in[21];
    const float* tW1 = (const float*)d_in[22];
    const float* tb1 = (const float*)d_in[23];
    const float* tW2 = (const float*)d_in[24];
    const float* tb2 = (const float*)d_in[25];
    const float* iW  = (const float*)d_in[26];
    const float* ib  = (const float*)d_in[27];
    const float* ilg = (const float*)d_in[28];
    const float* ilb = (const float*)d_in[29];
    const float* fW1 = (const float*)d_in[30];
    const float* fb1 = (const float*)d_in[31];
    const float* l1g = (const float*)d_in[32];
    const float* l1b = (const float*)d_in[33];
    const float* fW2 = (const float*)d_in[34];
    const float* fb2 = (const float*)d_in[35];
    const float* l2g = (const float*)d_in[36];
    const float* l2b = (const float*)d_in[37];
    const float* fW3 = (const float*)d_in[38];
    const float* fb3 = (const float*)d_in[39];
    float* out = (float*)d_out;

    const int N  = in_sizes[0] / 9;
    const int Ed = in_sizes[1] / 2;
    const int Es = in_sizes[4] / 2;
    const int B  = in_sizes[6];
    const int nb = (N + 255) / 256;

    char* w8 = (char*)d_ws;
    int* rpd   = (int*)w8;
    int* rps   = rpd + (N + 1);
    int* cntd  = rps + (N + 1);
    int* cnts  = cntd + N;
    int* cnt2d = cnts + N;
    int* cnt2s = cnt2d + N;
    int* sid   = cnt2s + N;
    int* sis   = sid + Ed;
    int* bsum  = sis + Es;
    size_t int_bytes = ((char*)(bsum + nb)) - w8;
    size_t foff = (int_bytes + 255) & ~(size_t)255;

    const int WT = 3 * NLAYER * 128 * 256;
    u16* W1t = (u16*)(w8 + foff);
    u16* W2t = W1t + WT;
    u16* hbase = W2t + WT;

    const size_t hS = (size_t)N * HID;
    const size_t need3 = foff + (size_t)2 * WT * 2 +
                         (size_t)3 * (hS * 2 + (size_t)N * 256) * 2 +
                         (size_t)3 * B * HID * 4 + 1024;
    const int ENC = (ws_size >= need3) ? 3 : 1;

    u16* hbuf  = hbase;
    u16* zbuf  = hbuf + (size_t)ENC * hS;
    u16* z2buf = zbuf + (size_t)ENC * hS;
    float* emb = (float*)(((uintptr_t)(z2buf + (size_t)ENC * (size_t)N * 256) + 255) & ~(uintptr_t)255);

    prep_weights<<<(2 * WT + 255) / 256, 256, 0, stream>>>(W1, W2, W1t, W2t);
    hipMemsetAsync(cntd, 0, (size_t)4 * N * sizeof(int), stream);
    hist_kernel<<<(Ed + 255) / 256, 256, 0, stream>>>(de, cntd, Ed);
    hist_kernel<<<(Es + 255) / 256, 256, 0, stream>>>(se, cnts, Es);
    scan1<<<nb, 256, 0, stream>>>(cntd, bsum, N);
    scan2<<<1, 256, 0, stream>>>(bsum, nb);
    scan3<<<nb, 256, 0, stream>>>(cntd, bsum, rpd, N, Ed);
    scan1<<<nb, 256, 0, stream>>>(cnts, bsum, N);
    scan2<<<1, 256, 0, stream>>>(bsum, nb);
    scan3<<<nb, 256, 0, stream>>>(cnts, bsum, rps, N, Es);
    fill_kernel<<<(Ed + 255) / 256, 256, 0, stream>>>(de, rpd, cnt2d, sid, Ed);
    fill_kernel<<<(Es + 255) / 256, 256, 0, stream>>>(se, rps, cnt2s, sis, Es);

    for (int e0 = 0; e0 < 3; e0 += ENC) {
        dim3 ga((N * HID + 255) / 256, 1, ENC);
        atom_kernel<<<ga, 256, 0, stream>>>(dx, sx, aW, ab, hbuf, N, e0);
        for (int l = 0; l < NLAYER; l++) {
            dim3 gg((N + 7) / 8, 1, ENC);
            gather_agg<<<gg, 256, 0, stream>>>(rpd, sid, rps, sis, hbuf, zbuf, eps, N, e0, l);
            dim3 gd1((N + 127) / 128, 2, ENC);
            gemm_mfma<128><<<gd1, 256, 0, stream>>>(zbuf, W1t, b1, g1, be1, m1, v1,
                                                    z2buf, N, 256, l, e0);
            dim3 gd2((N + 127) / 128, 1, ENC);
            gemm_mfma<256><<<gd2, 256, 0, stream>>>(z2buf, W2t, b2, g2, be2, m2, v2,
                                                    hbuf, N, 128, l, e0);
        }
        dim3 gp(B, 1, ENC);
        pool_kernel<<<gp, 128, 0, stream>>>(db, sb, hbuf, emb, N, B, e0);
    }
    fusion_kernel<<<B, 128, 0, stream>>>(emb, t, tW1, tb1, tW2, tb2,
                                         iW, ib, ilg, ilb, fW1, fb1, l1g, l1b,
                                         fW2, fb2, l2g, l2b, fW3, fb3, out, B);
}

// Round 4
// 825.846 us; speedup vs baseline: 16.4770x; 1.4468x over previous
//
#include <hip/hip_runtime.h>

#define HID 128
#define NLAYER 4

typedef unsigned short u16;
typedef __attribute__((ext_vector_type(8))) unsigned short u16x8;
typedef __attribute__((ext_vector_type(8))) short short8;
typedef __attribute__((ext_vector_type(4))) float floatx4;

__device__ __forceinline__ float bf2f(u16 u) {
    union { unsigned int i; float f; } v; v.i = ((unsigned int)u) << 16; return v.f;
}
__device__ __forceinline__ u16 f2bf(float f) {
    union { float f; unsigned int i; } v; v.f = f;
    unsigned int r = v.i + 0x7FFFu + ((v.i >> 16) & 1u);
    return (u16)(r >> 16);
}

// ---------------------------------------------------------------------------
__device__ __forceinline__ int lowbound(const int* __restrict__ a, int n, int v) {
    int lo = 0, hi = n;
    while (lo < hi) {
        int mid = (lo + hi) >> 1;
        if (a[mid] < v) lo = mid + 1; else hi = mid;
    }
    return lo;
}

// ---------------------------------------------------------------------------
// Weight prep: fp32 -> bf16, transposed to [enc][l][n][k].
// ---------------------------------------------------------------------------
__global__ void prep_weights(const float* __restrict__ W1, const float* __restrict__ W2,
                             u16* __restrict__ W1t, u16* __restrict__ W2t) {
    const int T = 3 * NLAYER * 128 * 256;  // 393216
    int o = blockIdx.x * blockDim.x + threadIdx.x;
    if (o < T) {
        int k = o & 127, n = (o >> 7) & 255, el = o >> 15;
        W1t[o] = f2bf(W1[((size_t)el * 128 + k) * 256 + n]);
    } else if (o < 2 * T) {
        int o2 = o - T;
        int k = o2 & 255, n = (o2 >> 8) & 127, el = o2 >> 15;
        W2t[o2] = f2bf(W2[((size_t)el * 256 + k) * 128 + n]);
    }
}

// ---------------------------------------------------------------------------
// CSR build, both graphs batched via grid.y
// ---------------------------------------------------------------------------
__global__ void hist2(const int* __restrict__ de, const int* __restrict__ se,
                      int* __restrict__ cntd, int* __restrict__ cnts, int Ed, int Es) {
    const int g = blockIdx.y;
    const int* ei = g ? se : de;
    int* cnt = g ? cnts : cntd;
    const int E = g ? Es : Ed;
    int e = blockIdx.x * 256 + threadIdx.x;
    if (e < E) atomicAdd(&cnt[ei[E + e]], 1);
}

__global__ __launch_bounds__(256) void scan1v(const int* __restrict__ cntd,
                                              const int* __restrict__ cnts,
                                              int* __restrict__ bsumd,
                                              int* __restrict__ bsums, int N) {
    const int g = blockIdx.y;
    const int* cnt = g ? cnts : cntd;
    int* bsum = g ? bsums : bsumd;
    __shared__ int s[256];
    int i = blockIdx.x * 256 + threadIdx.x;
    s[threadIdx.x] = (i < N) ? cnt[i] : 0;
    __syncthreads();
    for (int o = 128; o > 0; o >>= 1) {
        if (threadIdx.x < o) s[threadIdx.x] += s[threadIdx.x + o];
        __syncthreads();
    }
    if (threadIdx.x == 0) bsum[blockIdx.x] = s[0];
}

__global__ __launch_bounds__(256) void scan2v(int* __restrict__ bsumd,
                                              int* __restrict__ bsums, int nb) {
    int* bsum = blockIdx.x ? bsums : bsumd;
    __shared__ int s[256];
    __shared__ int carry;
    if (threadIdx.x == 0) carry = 0;
    __syncthreads();
    for (int base = 0; base < nb; base += 256) {
        int i = base + threadIdx.x;
        int v = (i < nb) ? bsum[i] : 0;
        s[threadIdx.x] = v;
        __syncthreads();
        for (int o = 1; o < 256; o <<= 1) {
            int tv = (threadIdx.x >= o) ? s[threadIdx.x - o] : 0;
            __syncthreads();
            s[threadIdx.x] += tv;
            __syncthreads();
        }
        int excl = carry + s[threadIdx.x] - v;
        if (i < nb) bsum[i] = excl;
        __syncthreads();
        if (threadIdx.x == 0) carry += s[255];
        __syncthreads();
    }
}

__global__ __launch_bounds__(256) void scan3v(const int* __restrict__ cntd,
                                              const int* __restrict__ cnts,
                                              const int* __restrict__ bsumd,
                                              const int* __restrict__ bsums,
                                              int* __restrict__ rpd, int* __restrict__ rps,
                                              int N, int Ed, int Es) {
    const int g = blockIdx.y;
    const int* cnt = g ? cnts : cntd;
    const int* bsum = g ? bsums : bsumd;
    int* rowptr = g ? rps : rpd;
    const int E = g ? Es : Ed;
    __shared__ int s[256];
    int i = blockIdx.x * 256 + threadIdx.x;
    int v = (i < N) ? cnt[i] : 0;
    s[threadIdx.x] = v;
    __syncthreads();
    for (int o = 1; o < 256; o <<= 1) {
        int tv = (threadIdx.x >= o) ? s[threadIdx.x - o] : 0;
        __syncthreads();
        s[threadIdx.x] += tv;
        __syncthreads();
    }
    if (i < N) rowptr[i] = bsum[blockIdx.x] + s[threadIdx.x] - v;
    if (i == 0 && blockIdx.x == 0) rowptr[N] = E;
}

__global__ void fill2(const int* __restrict__ de, const int* __restrict__ se,
                      const int* __restrict__ rpd, const int* __restrict__ rps,
                      int* __restrict__ cnt2d, int* __restrict__ cnt2s,
                      int* __restrict__ sid, int* __restrict__ sis, int Ed, int Es) {
    const int g = blockIdx.y;
    const int* ei = g ? se : de;
    const int* rowptr = g ? rps : rpd;
    int* cnt2 = g ? cnt2s : cnt2d;
    int* srcidx = g ? sis : sid;
    const int E = g ? Es : Ed;
    int e = blockIdx.x * 256 + threadIdx.x;
    if (e < E) {
        const int dst = ei[E + e];
        const int pos = rowptr[dst] + atomicAdd(&cnt2[dst], 1);
        srcidx[pos] = ei[e];
    }
}

// ---------------------------------------------------------------------------
// Atom encoder: h = x @ aW + ab  (fp32 compute, bf16 store). grid.z = slot.
// ---------------------------------------------------------------------------
__global__ void atom_kernel(const float* __restrict__ dx, const float* __restrict__ sx,
                            const float* __restrict__ aW, const float* __restrict__ ab,
                            u16* __restrict__ h, int N) {
    const int slot = blockIdx.z;
    long idx = (long)blockIdx.x * blockDim.x + threadIdx.x;
    if (idx >= (long)N * HID) return;
    const int n = (int)(idx / HID), c = (int)(idx % HID);
    const float* x = (slot < 2) ? dx : sx;
    const float* W = aW + (size_t)slot * 9 * HID;
    float acc = ab[slot * HID + c];
#pragma unroll
    for (int k = 0; k < 9; k++) acc = fmaf(x[n * 9 + k], W[k * HID + c], acc);
    h[(size_t)slot * N * HID + idx] = f2bf(acc);
}

// ---------------------------------------------------------------------------
// Gather-aggregate: z[n] = (1+eps)*h[n] + sum h[src].
// 16 lanes/node, 16 B loads, indices via coalesced load + shfl broadcast,
// edge loop unrolled x4 for MLP.
// ---------------------------------------------------------------------------
__global__ __launch_bounds__(256) void gather_agg(
    const int* __restrict__ rpd, const int* __restrict__ sid,
    const int* __restrict__ rps, const int* __restrict__ sis,
    const u16* __restrict__ h, u16* __restrict__ z,
    const float* __restrict__ eps, int N, int l) {
    const int slot = blockIdx.z;
    const int node = blockIdx.x * 16 + (threadIdx.x >> 4);
    if (node >= N) return;
    const int lane = threadIdx.x & 63;
    const int sl = lane & 15;
    const int subbase = lane & 48;  // 16-lane subgroup base within wave
    const int* rowptr = (slot < 2) ? rpd : rps;
    const int* srcidx = (slot < 2) ? sid : sis;
    const int lo = rowptr[node], hi = rowptr[node + 1];
    const u16* hp = h + (size_t)slot * N * HID;
    const int coff = sl * 8;

    u16x8 hv = *(const u16x8*)(hp + (size_t)node * HID + coff);
    const float scale = 1.f + eps[slot * NLAYER + l];
    float s[8];
#pragma unroll
    for (int i = 0; i < 8; i++) s[i] = bf2f(hv[i]) * scale;

    for (int base = lo; base < hi; base += 16) {
        const int cnt = min(16, hi - base);
        int idx = (sl < cnt) ? srcidx[base + sl] : 0;
        int j = 0;
        for (; j + 4 <= cnt; j += 4) {
            const int s0 = __shfl(idx, subbase + j);
            const int s1 = __shfl(idx, subbase + j + 1);
            const int s2 = __shfl(idx, subbase + j + 2);
            const int s3 = __shfl(idx, subbase + j + 3);
            u16x8 v0 = *(const u16x8*)(hp + (size_t)s0 * HID + coff);
            u16x8 v1 = *(const u16x8*)(hp + (size_t)s1 * HID + coff);
            u16x8 v2 = *(const u16x8*)(hp + (size_t)s2 * HID + coff);
            u16x8 v3 = *(const u16x8*)(hp + (size_t)s3 * HID + coff);
#pragma unroll
            for (int i = 0; i < 8; i++)
                s[i] += (bf2f(v0[i]) + bf2f(v1[i])) + (bf2f(v2[i]) + bf2f(v3[i]));
        }
        for (; j < cnt; j++) {
            const int sj = __shfl(idx, subbase + j);
            u16x8 v = *(const u16x8*)(hp + (size_t)sj * HID + coff);
#pragma unroll
            for (int i = 0; i < 8; i++) s[i] += bf2f(v[i]);
        }
    }
    u16x8 o;
#pragma unroll
    for (int i = 0; i < 8; i++) o[i] = f2bf(s[i]);
    *(u16x8*)(z + (size_t)slot * N * HID + (size_t)node * HID + coff) = o;
}

// ---------------------------------------------------------------------------
// Fused GIN layer: h_out = relu(BN2( relu(BN1(z@W1+b1)) @ W2 + b2 ))
// z: [slot][M][128] bf16.  W1t: [el][256][128], W2t: [el][128][256] bf16.
// Block 256 thr = 4 waves; tile 128 rows. One 34.8 KB LDS buffer reused:
//   stage z (stride 136 = 17-odd dwords: conflict-free b128) -> GEMM1 (acc in
//   regs, wave w owns cols {(c*4+w)*16+sl}) -> write z2 half (bf16) -> GEMM2
//   K-chunk -> write other half -> GEMM2 -> BN2 epilogue.
// MFMA 16x16x32 bf16, C/D: col=lane&15, row=(lane>>4)*4+reg [m89-verified].
// ---------------------------------------------------------------------------
__global__ __launch_bounds__(256, 2) void fused_layer(
    const u16* __restrict__ A, const u16* __restrict__ W1t, const u16* __restrict__ W2t,
    const float* __restrict__ b1, const float* __restrict__ g1, const float* __restrict__ be1,
    const float* __restrict__ m1, const float* __restrict__ v1,
    const float* __restrict__ b2, const float* __restrict__ g2, const float* __restrict__ be2,
    const float* __restrict__ m2, const float* __restrict__ v2,
    u16* __restrict__ out, int M, int l) {

    const int slot = blockIdx.z;
    const int m0 = blockIdx.x * 128;
    const u16* Ap  = A + (size_t)slot * M * 128;
    const int el = slot * NLAYER + l;
    const u16* Wp1 = W1t + (size_t)el * (256 * 128);
    const u16* Wp2 = W2t + (size_t)el * (128 * 256);
    const size_t poff1 = (size_t)el * 256;
    const size_t poff2 = (size_t)el * 128;

    __shared__ u16 sm[128 * 136];  // 34.8 KB, reused for z then z2 halves

    const int tid = threadIdx.x;
    const int lane = tid & 63;
    const int w = tid >> 6;
    const int sl = lane & 15;
    const int k8 = lane >> 4;

    // ---- stage z tile ----
    {
        const int rp = tid >> 4;
        const int kc = (tid & 15) * 8;
#pragma unroll
        for (int p = 0; p < 8; p++) {
            const int row = p * 16 + rp;
            int gr = m0 + row; if (gr >= M) gr = M - 1;
            *(uint4*)&sm[row * 136 + kc] = *(const uint4*)(Ap + (size_t)gr * 128 + kc);
        }
    }
    __syncthreads();

    // ---- GEMM1: 128 x 256, K=128 ----
    floatx4 acc1[8][4];
#pragma unroll
    for (int mt = 0; mt < 8; mt++)
#pragma unroll
        for (int c = 0; c < 4; c++) acc1[mt][c] = (floatx4)0.f;

#pragma unroll
    for (int ks = 0; ks < 4; ks++) {
        short8 a[8], b[4];
#pragma unroll
        for (int mt = 0; mt < 8; mt++)
            a[mt] = *(const short8*)&sm[(mt * 16 + sl) * 136 + ks * 32 + k8 * 8];
#pragma unroll
        for (int c = 0; c < 4; c++) {
            const int n = (c * 4 + w) * 16 + sl;
            b[c] = *(const short8*)(Wp1 + (size_t)n * 128 + ks * 32 + k8 * 8);
        }
#pragma unroll
        for (int mt = 0; mt < 8; mt++)
#pragma unroll
            for (int c = 0; c < 4; c++)
                acc1[mt][c] = __builtin_amdgcn_mfma_f32_16x16x32_bf16(a[mt], b[c], acc1[mt][c], 0, 0, 0);
    }
    __syncthreads();  // all waves done reading z tile

    // ---- z2 halves + GEMM2 ----
    const int wr = w & 1, wc = w >> 1;
    floatx4 acc2[4][4];
#pragma unroll
    for (int mt = 0; mt < 4; mt++)
#pragma unroll
        for (int nt = 0; nt < 4; nt++) acc2[mt][nt] = (floatx4)0.f;

#pragma unroll
    for (int part = 0; part < 2; part++) {
        // write z2 cols [part*128, part*128+128) after BN1+ReLU
#pragma unroll
        for (int c = part * 2; c < part * 2 + 2; c++) {
            const int gcol = (c * 4 + w) * 16 + sl;
            const int lcol = gcol - part * 128;
            const float sc = g1[poff1 + gcol] * rsqrtf(v1[poff1 + gcol] + 1e-5f);
            const float sh = (b1[poff1 + gcol] - m1[poff1 + gcol]) * sc + be1[poff1 + gcol];
#pragma unroll
            for (int mt = 0; mt < 8; mt++) {
#pragma unroll
                for (int r = 0; r < 4; r++) {
                    const int m = mt * 16 + k8 * 4 + r;
                    sm[m * 136 + lcol] = f2bf(fmaxf(fmaf(acc1[mt][c][r], sc, sh), 0.f));
                }
            }
        }
        __syncthreads();
        // GEMM2 over this K half
#pragma unroll
        for (int ks = 0; ks < 4; ks++) {
            short8 a[4], b[4];
#pragma unroll
            for (int mt = 0; mt < 4; mt++)
                a[mt] = *(const short8*)&sm[(wr * 64 + mt * 16 + sl) * 136 + ks * 32 + k8 * 8];
#pragma unroll
            for (int nt = 0; nt < 4; nt++) {
                const int n = wc * 64 + nt * 16 + sl;
                b[nt] = *(const short8*)(Wp2 + (size_t)n * 256 + part * 128 + ks * 32 + k8 * 8);
            }
#pragma unroll
            for (int mt = 0; mt < 4; mt++)
#pragma unroll
                for (int nt = 0; nt < 4; nt++)
                    acc2[mt][nt] = __builtin_amdgcn_mfma_f32_16x16x32_bf16(a[mt], b[nt], acc2[mt][nt], 0, 0, 0);
        }
        if (part == 0) __syncthreads();  // before overwriting z2 buffer
    }

    // ---- BN2 + ReLU epilogue ----
    u16* outp = out + (size_t)slot * M * 128;
#pragma unroll
    for (int nt = 0; nt < 4; nt++) {
        const int col = wc * 64 + nt * 16 + sl;
        const float sc = g2[poff2 + col] * rsqrtf(v2[poff2 + col] + 1e-5f);
        const float sh = (b2[poff2 + col] - m2[poff2 + col]) * sc + be2[poff2 + col];
#pragma unroll
        for (int mt = 0; mt < 4; mt++) {
#pragma unroll
            for (int r = 0; r < 4; r++) {
                const int gr = m0 + wr * 64 + mt * 16 + k8 * 4 + r;
                if (gr < M)
                    outp[(size_t)gr * 128 + col] = f2bf(fmaxf(fmaf(acc2[mt][nt][r], sc, sh), 0.f));
            }
        }
    }
}

// ---------------------------------------------------------------------------
// Segment-mean pool (bat sorted). bf16 in, fp32 out.
// ---------------------------------------------------------------------------
__global__ __launch_bounds__(128) void pool_kernel(const int* __restrict__ db,
                                                   const int* __restrict__ sb,
                                                   const u16* __restrict__ h,
                                                   float* __restrict__ emb,
                                                   int N, int B) {
    const int slot = blockIdx.z;
    const int* bat = (slot < 2) ? db : sb;
    const int g = blockIdx.x;
    const int lo = lowbound(bat, N, g);
    const int hi = lowbound(bat, N, g + 1);
    const int c = threadIdx.x;
    float s = 0.f;
    const u16* hp = h + (size_t)slot * N * HID;
    for (int n = lo; n < hi; n++) s += bf2f(hp[(size_t)n * HID + c]);
    const float cnt = (float)(hi - lo);
    emb[((size_t)slot * B + g) * HID + c] = s / fmaxf(cnt, 1.f);
}

// ---------------------------------------------------------------------------
__device__ __forceinline__ float block_sum128(float x, float* red, int tid) {
    red[tid] = x;
    __syncthreads();
    if (tid < 64) {
        float v = red[tid] + red[tid + 64];
#pragma unroll
        for (int o = 32; o > 0; o >>= 1) v += __shfl_down(v, o);
        if (tid == 0) red[0] = v;
    }
    __syncthreads();
    float r = red[0];
    __syncthreads();
    return r;
}

// ---------------------------------------------------------------------------
// Fusion head (fp32)
// ---------------------------------------------------------------------------
__global__ __launch_bounds__(128) void fusion_kernel(
    const float* __restrict__ emb, const float* __restrict__ t,
    const float* __restrict__ tW1, const float* __restrict__ tb1,
    const float* __restrict__ tW2, const float* __restrict__ tb2,
    const float* __restrict__ iW, const float* __restrict__ ib,
    const float* __restrict__ ilg, const float* __restrict__ ilb,
    const float* __restrict__ fW1, const float* __restrict__ fb1,
    const float* __restrict__ l1g, const float* __restrict__ l1b,
    const float* __restrict__ fW2, const float* __restrict__ fb2,
    const float* __restrict__ l2g, const float* __restrict__ l2b,
    const float* __restrict__ fW3, const float* __restrict__ fb3,
    float* __restrict__ out, int B) {
    const int r = blockIdx.x;
    const int tid = threadIdx.x;
    __shared__ float cs[256];
    __shared__ float cat[288];
    __shared__ float buf[128];
    __shared__ float red[128];
    __shared__ float tmp32[32];

    cs[tid]        = emb[((size_t)1 * B + r) * HID + tid];
    cs[128 + tid]  = emb[((size_t)2 * B + r) * HID + tid];
    cat[tid]       = emb[((size_t)0 * B + r) * HID + tid];
    __syncthreads();

    float acc = ib[tid];
    for (int k = 0; k < 256; k++) acc = fmaf(cs[k], iW[k * HID + tid], acc);
    float mu  = block_sum128(acc, red, tid) * (1.f / 128.f);
    float d   = acc - mu;
    float var = block_sum128(d * d, red, tid) * (1.f / 128.f);
    float inter = fmaxf(d * rsqrtf(var + 1e-5f) * ilg[tid] + ilb[tid], 0.f);
    cat[128 + tid] = inter;

    if (tid < 32) tmp32[tid] = fmaxf(fmaf(t[r], tW1[tid], tb1[tid]), 0.f);
    __syncthreads();
    if (tid < 32) {
        float a2 = tb2[tid];
        for (int j = 0; j < 32; j++) a2 = fmaf(tmp32[j], tW2[j * 32 + tid], a2);
        cat[256 + tid] = a2;
    }
    __syncthreads();

    float a1 = fb1[tid];
    for (int k = 0; k < 288; k++) a1 = fmaf(cat[k], fW1[k * HID + tid], a1);
    mu  = block_sum128(a1, red, tid) * (1.f / 128.f);
    d   = a1 - mu;
    var = block_sum128(d * d, red, tid) * (1.f / 128.f);
    buf[tid] = fmaxf(d * rsqrtf(var + 1e-5f) * l1g[tid] + l1b[tid], 0.f);
    __syncthreads();

    float a2v = 0.f;
    if (tid < 64) {
        a2v = fb2[tid];
        for (int k = 0; k < 128; k++) a2v = fmaf(buf[k], fW2[k * 64 + tid], a2v);
    }
    mu = block_sum128((tid < 64) ? a2v : 0.f, red, tid) * (1.f / 64.f);
    float d2 = (tid < 64) ? (a2v - mu) : 0.f;
    var = block_sum128(d2 * d2, red, tid) * (1.f / 64.f);
    float contrib = 0.f;
    if (tid < 64) {
        float h2 = fmaxf(d2 * rsqrtf(var + 1e-5f) * l2g[tid] + l2b[tid], 0.f);
        contrib = h2 * fW3[tid];
    }
    float s = block_sum128(contrib, red, tid);
    if (tid == 0) out[r] = s + fb3[0];
}

// ---------------------------------------------------------------------------
extern "C" void kernel_launch(void* const* d_in, const int* in_sizes, int n_in,
                              void* d_out, int out_size, void* d_ws, size_t ws_size,
                              hipStream_t stream) {
    const float* dx  = (const float*)d_in[0];
    const int*   de  = (const int*)d_in[1];
    const int*   db  = (const int*)d_in[2];
    const float* sx  = (const float*)d_in[3];
    const int*   se  = (const int*)d_in[4];
    const int*   sb  = (const int*)d_in[5];
    const float* t   = (const float*)d_in[6];
    const float* aW  = (const float*)d_in[7];
    const float* ab  = (const float*)d_in[8];
    const float* eps = (const float*)d_in[9];
    const float* W1  = (const float*)d_in[10];
    const float* b1  = (const float*)d_in[11];
    const float* g1  = (const float*)d_in[12];
    const float* be1 = (const float*)d_in[13];
    const float* m1  = (const float*)d_in[14];
    const float* v1  = (const float*)d_in[15];
    const float* W2  = (const float*)d_in[16];
    const float* b2  = (const float*)d_in[17];
    const float* g2  = (const float*)d_in[18];
    const float* be2 = (const float*)d_in[19];
    const float* m2  = (const float*)d_in[20];
    const float* v2  = (const float*)d_in[21];
    const float* tW1 = (const float*)d_in[22];
    const float* tb1 = (const float*)d_in[23];
    const float* tW2 = (const float*)d_in[24];
    const float* tb2 = (const float*)d_in[25];
    const float* iW  = (const float*)d_in[26];
    const float* ib  = (const float*)d_in[27];
    const float* ilg = (const float*)d_in[28];
    const float* ilb = (const float*)d_in[29];
    const float* fW1 = (const float*)d_in[30];
    const float* fb1 = (const float*)d_in[31];
    const float* l1g = (const float*)d_in[32];
    const float* l1b = (const float*)d_in[33];
    const float* fW2 = (const float*)d_in[34];
    const float* fb2 = (const float*)d_in[35];
    const float* l2g = (const float*)d_in[36];
    const float* l2b = (const float*)d_in[37];
    const float* fW3 = (const float*)d_in[38];
    const float* fb3 = (const float*)d_in[39];
    float* out = (float*)d_out;

    const int N  = in_sizes[0] / 9;
    const int Ed = in_sizes[1] / 2;
    const int Es = in_sizes[4] / 2;
    const int B  = in_sizes[6];
    const int nb = (N + 255) / 256;
    const int Emax = (Ed > Es) ? Ed : Es;

    // ---- workspace layout ----
    char* w8 = (char*)d_ws;
    int* rpd   = (int*)w8;
    int* rps   = rpd + (N + 1);
    int* cntd  = rps + (N + 1);
    int* cnts  = cntd + N;
    int* cnt2d = cnts + N;
    int* cnt2s = cnt2d + N;
    int* sid   = cnt2s + N;
    int* sis   = sid + Ed;
    int* bsumd = sis + Es;
    int* bsums = bsumd + nb;
    size_t int_bytes = ((char*)(bsums + nb)) - w8;
    size_t foff = (int_bytes + 255) & ~(size_t)255;

    const int WT = 3 * NLAYER * 128 * 256;
    u16* W1t = (u16*)(w8 + foff);
    u16* W2t = W1t + WT;
    const size_t hS = (size_t)N * HID;
    u16* hbuf = W2t + WT;
    u16* zbuf = hbuf + 3 * hS;
    float* emb = (float*)(((uintptr_t)(zbuf + 3 * hS) + 255) & ~(uintptr_t)255);

    // ---- weight prep + CSR build ----
    prep_weights<<<(2 * WT + 255) / 256, 256, 0, stream>>>(W1, W2, W1t, W2t);
    hipMemsetAsync(cntd, 0, (size_t)4 * N * sizeof(int), stream);
    {
        dim3 gh((Emax + 255) / 256, 2);
        hist2<<<gh, 256, 0, stream>>>(de, se, cntd, cnts, Ed, Es);
        dim3 gs1(nb, 2);
        scan1v<<<gs1, 256, 0, stream>>>(cntd, cnts, bsumd, bsums, N);
        scan2v<<<2, 256, 0, stream>>>(bsumd, bsums, nb);
        scan3v<<<gs1, 256, 0, stream>>>(cntd, cnts, bsumd, bsums, rpd, rps, N, Ed, Es);
        fill2<<<gh, 256, 0, stream>>>(de, se, rpd, rps, cnt2d, cnt2s, sid, sis, Ed, Es);
    }

    // ---- encoders (all 3 slots batched via grid.z) ----
    {
        dim3 ga((N * HID + 255) / 256, 1, 3);
        atom_kernel<<<ga, 256, 0, stream>>>(dx, sx, aW, ab, hbuf, N);
        for (int l = 0; l < NLAYER; l++) {
            dim3 gg((N + 15) / 16, 1, 3);
            gather_agg<<<gg, 256, 0, stream>>>(rpd, sid, rps, sis, hbuf, zbuf, eps, N, l);
            dim3 gf((N + 127) / 128, 1, 3);
            fused_layer<<<gf, 256, 0, stream>>>(zbuf, W1t, W2t,
                                                b1, g1, be1, m1, v1,
                                                b2, g2, be2, m2, v2,
                                                hbuf, N, l);
        }
        dim3 gp(B, 1, 3);
        pool_kernel<<<gp, 128, 0, stream>>>(db, sb, hbuf, emb, N, B);
    }
    fusion_kernel<<<B, 128, 0, stream>>>(emb, t, tW1, tb1, tW2, tb2,
                                         iW, ib, ilg, ilb, fW1, fb1, l1g, l1b,
                                         fW2, fb2, l2g, l2b, fW3, fb3, out, B);
}